// Round 1
// baseline (591.440 us; speedup 1.0000x reference)
//
#include <hip/hip_runtime.h>
#include <hip/hip_bf16.h>

// Problem constants
#define B_   2
#define S_   2048
#define C_   2048
#define H_   16
#define DH   128
#define C3   (3 * C_)

typedef __attribute__((ext_vector_type(8))) short short8;
typedef __attribute__((ext_vector_type(4))) float floatx4;

__device__ __forceinline__ void gload16(const void* g, void* l) {
  __builtin_amdgcn_global_load_lds(
      (const __attribute__((address_space(1))) unsigned int*)g,
      (__attribute__((address_space(3))) unsigned int*)l, 16, 0, 0);
}

// ---------------- cast f32 -> bf16 ----------------
__global__ __launch_bounds__(256) void cast_bf16_kernel(
    const float* __restrict__ in, __hip_bfloat16* __restrict__ out, int n4) {
  int i = blockIdx.x * blockDim.x + threadIdx.x;
  if (i >= n4) return;
  float4 v = ((const float4*)in)[i];
  union { __hip_bfloat16 b[4]; uint2 u; } t;
  t.b[0] = __float2bfloat16(v.x);
  t.b[1] = __float2bfloat16(v.y);
  t.b[2] = __float2bfloat16(v.z);
  t.b[3] = __float2bfloat16(v.w);
  ((uint2*)out)[i] = t.u;
}

// ---------------- transpose + cast: in[R][Cc] f32 -> out[Cc][R] bf16 ----------------
__global__ __launch_bounds__(256) void transpose_cast_kernel(
    const float* __restrict__ in, __hip_bfloat16* __restrict__ out, int R, int Cc) {
  __shared__ float tile[32][33];
  int c0 = blockIdx.x * 32, r0 = blockIdx.y * 32;
  int tx = threadIdx.x & 31, ty = threadIdx.x >> 5;  // ty: 0..7
#pragma unroll
  for (int k = 0; k < 4; ++k)
    tile[ty + 8 * k][tx] = in[(size_t)(r0 + ty + 8 * k) * Cc + c0 + tx];
  __syncthreads();
#pragma unroll
  for (int k = 0; k < 4; ++k)
    out[(size_t)(c0 + ty + 8 * k) * R + r0 + tx] = __float2bfloat16(tile[tx][ty + 8 * k]);
}

// ---------------- GEMM: C[M][N] = A[M][K] * Bt[N][K]^T  (m97 structure) ----------------
// A,Bt bf16 row-major; 128x128 tile, BK=32, 256 threads (4 waves, 2x2 wave grid).
template <bool OUT_F32>
__global__ __launch_bounds__(256) void gemm_bt_kernel(
    const __hip_bfloat16* __restrict__ A, const __hip_bfloat16* __restrict__ Bt,
    void* __restrict__ Cp, int M, int N, int K) {
  __shared__ __hip_bfloat16 As[128 * 32];
  __shared__ __hip_bfloat16 Bs[128 * 32];
  const int tid = threadIdx.x;
  const int lane = tid & 63, wv = tid >> 6;
  const int wm = wv >> 1, wn = wv & 1;
  const int lr = lane & 15, lq = lane >> 4;
  const int m0 = blockIdx.y * 128, n0 = blockIdx.x * 128;

  floatx4 acc[4][4] = {};

  for (int k0 = 0; k0 < K; k0 += 32) {
    // stage A and Bt tiles: packed 16B chunks, chunk c -> row c>>2, k-off (c&3)*8
#pragma unroll
    for (int p = 0; p < 2; ++p) {
      int c = p * 256 + wv * 64 + lane;
      int row = c >> 2, ko = (c & 3) << 3;
      gload16(A + (size_t)(m0 + row) * K + k0 + ko,
              (char*)As + (size_t)(p * 256 + wv * 64) * 16);
      gload16(Bt + (size_t)(n0 + row) * K + k0 + ko,
              (char*)Bs + (size_t)(p * 256 + wv * 64) * 16);
    }
    __syncthreads();
    short8 af[4], bf[4];
#pragma unroll
    for (int i = 0; i < 4; ++i)
      af[i] = *(const short8*)(As + (wm * 64 + i * 16 + lr) * 32 + lq * 8);
#pragma unroll
    for (int j = 0; j < 4; ++j)
      bf[j] = *(const short8*)(Bs + (wn * 64 + j * 16 + lr) * 32 + lq * 8);
#pragma unroll
    for (int i = 0; i < 4; ++i)
#pragma unroll
      for (int j = 0; j < 4; ++j)
        acc[i][j] = __builtin_amdgcn_mfma_f32_16x16x32_bf16(af[i], bf[j], acc[i][j], 0, 0, 0);
    __syncthreads();
  }

  // epilogue: C/D layout col=lane&15, row=(lane>>4)*4+reg
#pragma unroll
  for (int i = 0; i < 4; ++i)
#pragma unroll
    for (int j = 0; j < 4; ++j)
#pragma unroll
      for (int r = 0; r < 4; ++r) {
        int row = m0 + wm * 64 + i * 16 + lq * 4 + r;
        int col = n0 + wn * 64 + j * 16 + lr;
        if (OUT_F32)
          ((float*)Cp)[(size_t)row * N + col] = acc[i][j][r];
        else
          ((__hip_bfloat16*)Cp)[(size_t)row * N + col] = __float2bfloat16(acc[i][j][r]);
      }
}

// ---------------- RoPE over k (cols 0..C) and q (cols C..2C) of qkv; scales q ----------------
__global__ __launch_bounds__(256) void rope_kernel(__hip_bfloat16* __restrict__ qkv) {
  int i = blockIdx.x * blockDim.x + threadIdx.x;  // B*S*H*64 threads
  int d = i & 63;
  int h = (i >> 6) & 15;
  int row = i >> 10;        // 0..4095
  int s = row & (S_ - 1);
  float invf = powf(10000.0f, -(float)d * (1.0f / 64.0f));
  float ang = (float)s * invf;
  float c = cosf(ang), sn = sinf(ang);
  size_t base = (size_t)row * C3 + h * DH + d;
  float k1 = __bfloat162float(qkv[base]);
  float k2 = __bfloat162float(qkv[base + 64]);
  qkv[base]      = __float2bfloat16(k1 * c - k2 * sn);
  qkv[base + 64] = __float2bfloat16(k2 * c + k1 * sn);
  const float scale = 0.08838834764831845f;  // 1/sqrt(128)
  float q1 = __bfloat162float(qkv[base + C_]);
  float q2 = __bfloat162float(qkv[base + C_ + 64]);
  qkv[base + C_]      = __float2bfloat16((q1 * c - q2 * sn) * scale);
  qkv[base + C_ + 64] = __float2bfloat16((q2 * c + q1 * sn) * scale);
}

// ---------------- Flash attention: qkv (k|q|v, rope'd, q pre-scaled) -> out bf16 ----------------
// Grid: (S/128, B*H). Block 256 = 4 waves; wave w owns 32 q-rows. BKT=64.
__global__ __launch_bounds__(256) void attn_kernel(
    const __hip_bfloat16* __restrict__ qkv, __hip_bfloat16* __restrict__ outp) {
  __shared__ __hip_bfloat16 Ks[64 * 136];   // [s][d], pitch 136
  __shared__ __hip_bfloat16 Vt[128 * 72];   // [d][s], pitch 72
  __shared__ __hip_bfloat16 Ps[4 * 32 * 72];// per-wave 32 rows, pitch 72

  const int tid = threadIdx.x, lane = tid & 63, wv = tid >> 6;
  const int lr = lane & 15, lq = lane >> 4;
  const int qt = gridDim.x - 1 - blockIdx.x;  // heavy tiles first
  const int bh = blockIdx.y;
  const int b = bh >> 4, h = bh & 15;
  const int q0 = qt * 128;
  const size_t brow = (size_t)b * S_;

  // Q fragments in registers (A-layout): rows q0+wv*32 .. +32
  short8 qf[2][4];
#pragma unroll
  for (int rt = 0; rt < 2; ++rt)
#pragma unroll
    for (int ks = 0; ks < 4; ++ks) {
      int row = q0 + wv * 32 + rt * 16 + lr;
      qf[rt][ks] = *(const short8*)(qkv + (size_t)(brow + row) * C3 + C_ + h * DH + ks * 32 + lq * 8);
    }

  floatx4 of[2][8] = {};
  float m_run[2][4], l_run[2][4];
#pragma unroll
  for (int rt = 0; rt < 2; ++rt)
#pragma unroll
    for (int r = 0; r < 4; ++r) { m_run[rt][r] = -1e30f; l_run[rt][r] = 0.0f; }

  const int wrow_last = q0 + wv * 32 + 31;
  const int nkt = (q0 + 128) >> 6;

  for (int kt = 0; kt < nkt; ++kt) {
    const int kb = kt << 6;
    // stage K tile [64][128] -> Ks (padded)
#pragma unroll
    for (int p = 0; p < 4; ++p) {
      int c = p * 256 + tid;
      int srow = c >> 4, dk = (c & 15) << 3;
      short8 kv = *(const short8*)(qkv + (size_t)(brow + kb + srow) * C3 + h * DH + dk);
      *(short8*)(Ks + srow * 136 + dk) = kv;
    }
    // stage V^T: pair-pack two s-rows into dword writes
#pragma unroll
    for (int i2 = 0; i2 < 2; ++i2) {
      int sp = (tid & 15) + 16 * i2;
      int dc = tid >> 4;
      int sl = sp * 2, d0 = dc * 8;
      const __hip_bfloat16* vg = qkv + (size_t)(brow + kb + sl) * C3 + 2 * C_ + h * DH + d0;
      short8 r0 = *(const short8*)vg;
      short8 r1 = *(const short8*)(vg + C3);
#pragma unroll
      for (int j = 0; j < 8; ++j) {
        unsigned int dw = (unsigned short)r0[j] | ((unsigned int)(unsigned short)r1[j] << 16);
        *(unsigned int*)(Vt + (d0 + j) * 72 + sl) = dw;
      }
    }
    __syncthreads();

    if (kb <= wrow_last) {  // wave-uniform
      // S = Q K^T (contraction over Dh=128)
      floatx4 sf[2][4] = {};
#pragma unroll
      for (int ks = 0; ks < 4; ++ks) {
        short8 bfr[4];
#pragma unroll
        for (int ct = 0; ct < 4; ++ct)
          bfr[ct] = *(const short8*)(Ks + (ct * 16 + lr) * 136 + ks * 32 + lq * 8);
#pragma unroll
        for (int rt = 0; rt < 2; ++rt)
#pragma unroll
          for (int ct = 0; ct < 4; ++ct)
            sf[rt][ct] = __builtin_amdgcn_mfma_f32_16x16x32_bf16(qf[rt][ks], bfr[ct], sf[rt][ct], 0, 0, 0);
      }
      // causal mask
#pragma unroll
      for (int rt = 0; rt < 2; ++rt)
#pragma unroll
        for (int ct = 0; ct < 4; ++ct)
#pragma unroll
          for (int r = 0; r < 4; ++r) {
            int col = kb + ct * 16 + lr;
            int row = q0 + wv * 32 + rt * 16 + lq * 4 + r;
            if (col > row) sf[rt][ct][r] = -1e30f;
          }
      // online softmax (row groups of 16 lanes share lq)
#pragma unroll
      for (int rt = 0; rt < 2; ++rt) {
#pragma unroll
        for (int r = 0; r < 4; ++r) {
          float tm = fmaxf(fmaxf(sf[rt][0][r], sf[rt][1][r]), fmaxf(sf[rt][2][r], sf[rt][3][r]));
#pragma unroll
          for (int off = 1; off < 16; off <<= 1)
            tm = fmaxf(tm, __shfl_xor(tm, off, 64));
          float mn = fmaxf(m_run[rt][r], tm);
          float al = __expf(m_run[rt][r] - mn);
          m_run[rt][r] = mn;
          float s = 0.0f;
#pragma unroll
          for (int ct = 0; ct < 4; ++ct) {
            float pv = __expf(sf[rt][ct][r] - mn);
            sf[rt][ct][r] = pv;
            s += pv;
          }
#pragma unroll
          for (int off = 1; off < 16; off <<= 1)
            s += __shfl_xor(s, off, 64);
          l_run[rt][r] = l_run[rt][r] * al + s;
#pragma unroll
          for (int dt = 0; dt < 8; ++dt) of[rt][dt][r] *= al;
          // write P row to per-wave LDS region (C-layout row)
          int lrow = wv * 32 + rt * 16 + lq * 4 + r;
#pragma unroll
          for (int ct = 0; ct < 4; ++ct)
            Ps[lrow * 72 + ct * 16 + lr] = __float2bfloat16(sf[rt][ct][r]);
        }
      }
      // O += P V (contraction over 64)
#pragma unroll
      for (int ks = 0; ks < 2; ++ks) {
        short8 pa[2], vb[8];
#pragma unroll
        for (int rt = 0; rt < 2; ++rt)
          pa[rt] = *(const short8*)(Ps + (wv * 32 + rt * 16 + lr) * 72 + ks * 32 + lq * 8);
#pragma unroll
        for (int dt = 0; dt < 8; ++dt)
          vb[dt] = *(const short8*)(Vt + (dt * 16 + lr) * 72 + ks * 32 + lq * 8);
#pragma unroll
        for (int rt = 0; rt < 2; ++rt)
#pragma unroll
          for (int dt = 0; dt < 8; ++dt)
            of[rt][dt] = __builtin_amdgcn_mfma_f32_16x16x32_bf16(pa[rt], vb[dt], of[rt][dt], 0, 0, 0);
      }
    }
    __syncthreads();
  }

  // epilogue: O /= l, store bf16
#pragma unroll
  for (int rt = 0; rt < 2; ++rt) {
    float inv[4];
#pragma unroll
    for (int r = 0; r < 4; ++r) inv[r] = 1.0f / l_run[rt][r];
#pragma unroll
    for (int dt = 0; dt < 8; ++dt)
#pragma unroll
      for (int r = 0; r < 4; ++r) {
        int row = q0 + wv * 32 + rt * 16 + lq * 4 + r;
        int col = h * DH + dt * 16 + lr;
        outp[(size_t)(brow + row) * C_ + col] = __float2bfloat16(of[rt][dt][r] * inv[r]);
      }
  }
}

extern "C" void kernel_launch(void* const* d_in, const int* in_sizes, int n_in,
                              void* d_out, int out_size, void* d_ws, size_t ws_size,
                              hipStream_t stream) {
  const float* x = (const float*)d_in[0];      // [4096][2048]
  const float* Wqkv = (const float*)d_in[1];   // [2048][6144]
  const float* Wproj = (const float*)d_in[2];  // [2048][2048]
  float* out = (float*)d_out;                  // [4096][2048] f32

  // workspace layout (bf16), with reuse: attnb overlays xb, WprojT overlays WqkvT
  __hip_bfloat16* xb = (__hip_bfloat16*)d_ws;              // 4096*2048
  __hip_bfloat16* WqkvT = xb + (size_t)4096 * 2048;        // 6144*2048
  __hip_bfloat16* qkvb = WqkvT + (size_t)6144 * 2048;      // 4096*6144
  __hip_bfloat16* WprojT = WqkvT;                          // 2048*2048 (after GEMM1)
  __hip_bfloat16* attnb = xb;                              // 4096*2048 (after GEMM1)

  // 1. casts / transposes
  cast_bf16_kernel<<<8192, 256, 0, stream>>>(x, xb, (4096 * 2048) / 4);
  transpose_cast_kernel<<<dim3(6144 / 32, 2048 / 32), 256, 0, stream>>>(Wqkv, WqkvT, 2048, 6144);

  // 2. qkv = x @ Wqkv   (M=4096, N=6144, K=2048) -> bf16
  gemm_bt_kernel<false><<<dim3(6144 / 128, 4096 / 128), 256, 0, stream>>>(
      xb, WqkvT, (void*)qkvb, 4096, 6144, 2048);

  // 3. RoPE on k and q regions (q pre-scaled by 1/sqrt(Dh))
  rope_kernel<<<(B_ * S_ * H_ * 64) / 256, 256, 0, stream>>>(qkvb);

  // 4. Wproj transpose (into WqkvT's old space — dead after GEMM1)
  transpose_cast_kernel<<<dim3(2048 / 32, 2048 / 32), 256, 0, stream>>>(Wproj, WprojT, 2048, 2048);

  // 5. flash attention -> attnb (overlays xb — dead after GEMM1)
  attn_kernel<<<dim3(S_ / 128, B_ * H_), 256, 0, stream>>>(qkvb, attnb);

  // 6. out = attnb @ Wproj  (M=4096, N=2048, K=2048) -> f32 d_out
  gemm_bt_kernel<true><<<dim3(2048 / 128, 4096 / 128), 256, 0, stream>>>(
      attnb, WprojT, d_out, 4096, 2048, 2048);
}

// Round 2
// 473.129 us; speedup vs baseline: 1.2501x; 1.2501x over previous
//
#include <hip/hip_runtime.h>
#include <hip/hip_bf16.h>

// Problem constants
#define B_   2
#define S_   2048
#define C_   2048
#define H_   16
#define DH   128
#define C3   (3 * C_)

typedef __attribute__((ext_vector_type(8))) short short8;
typedef __attribute__((ext_vector_type(4))) float floatx4;

__device__ __forceinline__ void gload16(const void* g, void* l) {
  __builtin_amdgcn_global_load_lds(
      (const __attribute__((address_space(1))) unsigned int*)g,
      (__attribute__((address_space(3))) unsigned int*)l, 16, 0, 0);
}

__device__ __forceinline__ unsigned pk_bf16(float a, float b) {
  union { __hip_bfloat16 h; unsigned short u; } ua, ub;
  ua.h = __float2bfloat16(a); ub.h = __float2bfloat16(b);
  return (unsigned)ua.u | ((unsigned)ub.u << 16);
}

// ---------------- cast f32 -> bf16 ----------------
__global__ __launch_bounds__(256) void cast_bf16_kernel(
    const float* __restrict__ in, __hip_bfloat16* __restrict__ out, int n4) {
  int i = blockIdx.x * blockDim.x + threadIdx.x;
  if (i >= n4) return;
  float4 v = ((const float4*)in)[i];
  union { __hip_bfloat16 b[4]; uint2 u; } t;
  t.b[0] = __float2bfloat16(v.x);
  t.b[1] = __float2bfloat16(v.y);
  t.b[2] = __float2bfloat16(v.z);
  t.b[3] = __float2bfloat16(v.w);
  ((uint2*)out)[i] = t.u;
}

// ---------------- transpose + cast: in[R][Cc] f32 -> out[Cc][R] bf16 ----------------
__global__ __launch_bounds__(256) void transpose_cast_kernel(
    const float* __restrict__ in, __hip_bfloat16* __restrict__ out, int R, int Cc) {
  __shared__ float tile[32][33];
  int c0 = blockIdx.x * 32, r0 = blockIdx.y * 32;
  int tx = threadIdx.x & 31, ty = threadIdx.x >> 5;  // ty: 0..7
#pragma unroll
  for (int k = 0; k < 4; ++k)
    tile[ty + 8 * k][tx] = in[(size_t)(r0 + ty + 8 * k) * Cc + c0 + tx];
  __syncthreads();
#pragma unroll
  for (int k = 0; k < 4; ++k)
    out[(size_t)(c0 + ty + 8 * k) * R + r0 + tx] = __float2bfloat16(tile[tx][ty + 8 * k]);
}

// ---------------- GEMM: C[M][N] = A[M][K] * Bt[N][K]^T  (m97 structure) ----------------
template <bool OUT_F32>
__global__ __launch_bounds__(256) void gemm_bt_kernel(
    const __hip_bfloat16* __restrict__ A, const __hip_bfloat16* __restrict__ Bt,
    void* __restrict__ Cp, int M, int N, int K) {
  __shared__ __hip_bfloat16 As[128 * 32];
  __shared__ __hip_bfloat16 Bs[128 * 32];
  const int tid = threadIdx.x;
  const int lane = tid & 63, wv = tid >> 6;
  const int wm = wv >> 1, wn = wv & 1;
  const int lr = lane & 15, lq = lane >> 4;
  const int m0 = blockIdx.y * 128, n0 = blockIdx.x * 128;

  floatx4 acc[4][4] = {};

  for (int k0 = 0; k0 < K; k0 += 32) {
#pragma unroll
    for (int p = 0; p < 2; ++p) {
      int c = p * 256 + wv * 64 + lane;
      int row = c >> 2, ko = (c & 3) << 3;
      gload16(A + (size_t)(m0 + row) * K + k0 + ko,
              (char*)As + (size_t)(p * 256 + wv * 64) * 16);
      gload16(Bt + (size_t)(n0 + row) * K + k0 + ko,
              (char*)Bs + (size_t)(p * 256 + wv * 64) * 16);
    }
    __syncthreads();
    short8 af[4], bf[4];
#pragma unroll
    for (int i = 0; i < 4; ++i)
      af[i] = *(const short8*)(As + (wm * 64 + i * 16 + lr) * 32 + lq * 8);
#pragma unroll
    for (int j = 0; j < 4; ++j)
      bf[j] = *(const short8*)(Bs + (wn * 64 + j * 16 + lr) * 32 + lq * 8);
#pragma unroll
    for (int i = 0; i < 4; ++i)
#pragma unroll
      for (int j = 0; j < 4; ++j)
        acc[i][j] = __builtin_amdgcn_mfma_f32_16x16x32_bf16(af[i], bf[j], acc[i][j], 0, 0, 0);
    __syncthreads();
  }

#pragma unroll
  for (int i = 0; i < 4; ++i)
#pragma unroll
    for (int j = 0; j < 4; ++j)
#pragma unroll
      for (int r = 0; r < 4; ++r) {
        int row = m0 + wm * 64 + i * 16 + lq * 4 + r;
        int col = n0 + wn * 64 + j * 16 + lr;
        if (OUT_F32)
          ((float*)Cp)[(size_t)row * N + col] = acc[i][j][r];
        else
          ((__hip_bfloat16*)Cp)[(size_t)row * N + col] = __float2bfloat16(acc[i][j][r]);
      }
}

// ---------------- RoPE over k (cols 0..C) and q (cols C..2C) of qkv; scales q ----------------
__global__ __launch_bounds__(256) void rope_kernel(__hip_bfloat16* __restrict__ qkv) {
  int i = blockIdx.x * blockDim.x + threadIdx.x;  // B*S*H*64 threads
  int d = i & 63;
  int h = (i >> 6) & 15;
  int row = i >> 10;        // 0..4095
  int s = row & (S_ - 1);
  float invf = exp2f((float)d * (-13.287712379549449f / 64.0f));  // 10000^(-d/64)
  float ang = (float)s * invf;
  float sn, c;
  __sincosf(ang, &sn, &c);
  size_t base = (size_t)row * C3 + h * DH + d;
  float k1 = __bfloat162float(qkv[base]);
  float k2 = __bfloat162float(qkv[base + 64]);
  qkv[base]      = __float2bfloat16(k1 * c - k2 * sn);
  qkv[base + 64] = __float2bfloat16(k2 * c + k1 * sn);
  const float scale = 0.08838834764831845f;  // 1/sqrt(128)
  float q1 = __bfloat162float(qkv[base + C_]);
  float q2 = __bfloat162float(qkv[base + C_ + 64]);
  qkv[base + C_]      = __float2bfloat16((q1 * c - q2 * sn) * scale);
  qkv[base + C_ + 64] = __float2bfloat16((q2 * c + q1 * sn) * scale);
}

// ---------------- V pre-transpose into tiled [bh][kt][chunk16] layout ----------------
// Tile (bh, t): V^T block [128 d][64 s]; chunk L = cs*128 + d holds V[t*64+cs*8+j][d], j=0..7.
__global__ __launch_bounds__(256) void vtrans_kernel(
    const __hip_bfloat16* __restrict__ qkv, __hip_bfloat16* __restrict__ vt) {
  __shared__ short T[64 * 144];  // [s][d], pitch 144 (16B-aligned rows)
  const int tid = threadIdx.x;
  const int t = blockIdx.x, bh = blockIdx.y;
  const int b = bh >> 4, h = bh & 15;
  const size_t brow = (size_t)b * S_;
#pragma unroll
  for (int p = 0; p < 4; ++p) {
    int idx = p * 256 + tid;
    int row = idx >> 4, c8 = idx & 15;
    *(short8*)(T + row * 144 + c8 * 8) =
        *(const short8*)(qkv + (brow + t * 64 + row) * C3 + 2 * C_ + h * DH + c8 * 8);
  }
  __syncthreads();
#pragma unroll
  for (int p = 0; p < 4; ++p) {
    int L = p * 256 + tid;
    int d = L & 127, cs = L >> 7;
    short8 v;
#pragma unroll
    for (int j = 0; j < 8; ++j) v[j] = T[(cs * 8 + j) * 144 + d];
    *(short8*)(vt + ((size_t)bh * 32 + t) * 8192 + (size_t)L * 8) = v;
  }
}

// ---------------- Flash attention (transposed-S formulation) ----------------
// Grid (32 qtiles, 32 bh), block 256 = 4 waves; wave owns 16 q-rows. BKT=64.
// St = mfma(Kfrag, Qfrag): k in regs, q in lanes -> softmax is per-lane scalar chain.
__global__ __launch_bounds__(256, 3) void attn_kernel(
    const __hip_bfloat16* __restrict__ qkv,
    const __hip_bfloat16* __restrict__ vt_tiles,
    __hip_bfloat16* __restrict__ outp) {
  __shared__ __hip_bfloat16 Ks[64 * 128];   // xor-swizzled 16B chunks: L = srow*16 + (ck ^ (srow&15))
  __shared__ __hip_bfloat16 Vt[64 * 128];   // chunk L = cs*128 + d (matches vt_tiles)
  __shared__ __hip_bfloat16 Ps[4 * 16 * 72];// per-wave P [16 q][64 s], pitch 72

  const int tid = threadIdx.x, lane = tid & 63, wv = tid >> 6;
  const int lr = lane & 15, lq = lane >> 4;
  const int qt = gridDim.x - 1 - blockIdx.x;  // heavy tiles first
  const int bh = blockIdx.y;
  const int b = bh >> 4, h = bh & 15;
  const int q0 = qt * 64;
  const int q0w = q0 + wv * 16;
  const size_t brow = (size_t)b * S_;

  // Q fragments (A/B-operand layout): row q = q0w + lr, k-chunk lq*8
  short8 qf[4];
#pragma unroll
  for (int ks = 0; ks < 4; ++ks)
    qf[ks] = *(const short8*)(qkv + (brow + q0w + lr) * C3 + C_ + h * DH + ks * 32 + lq * 8);

  floatx4 of[8] = {};            // O accum: q = lq*4+r (regs), d = dt*16+lr
  float m_run = -1e30f, l_run = 0.0f;  // per-lane, for q = q0w + lr

  const int nkt = qt + 1;
  for (int kt = 0; kt < nkt; ++kt) {
    const int kb = kt * 64;
    // ---- stage K (swizzled) and V (pre-tiled) via async DMA ----
#pragma unroll
    for (int p = 0; p < 4; ++p) {
      int L = p * 256 + wv * 64 + lane;
      int srow = L >> 4;
      int ck = (L & 15) ^ (srow & 15);
      gload16(qkv + (brow + kb + srow) * C3 + h * DH + ck * 8,
              (char*)Ks + (size_t)(p * 256 + wv * 64) * 16);
      gload16(vt_tiles + ((size_t)bh * 32 + kt) * 8192 + (size_t)L * 8,
              (char*)Vt + (size_t)(p * 256 + wv * 64) * 16);
    }
    __syncthreads();

    // ---- St = K Q^T : St[t4][r] -> s = kb + t4*16 + lq*4 + r, q = q0w + lr ----
    floatx4 st[4] = {};
#pragma unroll
    for (int ks = 0; ks < 4; ++ks) {
      short8 kfr[4];
#pragma unroll
      for (int t4 = 0; t4 < 4; ++t4)
        kfr[t4] = *(const short8*)(Ks + ((t4 * 16 + lr) * 16 + ((ks * 4 + lq) ^ lr)) * 8);
#pragma unroll
      for (int t4 = 0; t4 < 4; ++t4)
        st[t4] = __builtin_amdgcn_mfma_f32_16x16x32_bf16(kfr[t4], qf[ks], st[t4], 0, 0, 0);
    }

    // ---- causal mask (only the diagonal tile) ----
    if (kt == nkt - 1) {
#pragma unroll
      for (int t4 = 0; t4 < 4; ++t4)
#pragma unroll
        for (int r = 0; r < 4; ++r) {
          int s = kb + t4 * 16 + lq * 4 + r;
          if (s > q0w + lr) st[t4][r] = -1e30f;
        }
    }

    // ---- online softmax: one scalar chain per lane ----
    float tm = -1e30f;
#pragma unroll
    for (int t4 = 0; t4 < 4; ++t4)
#pragma unroll
      for (int r = 0; r < 4; ++r) tm = fmaxf(tm, st[t4][r]);
    tm = fmaxf(tm, __shfl_xor(tm, 16));
    tm = fmaxf(tm, __shfl_xor(tm, 32));
    float mn = fmaxf(m_run, tm);
    float al = __expf(m_run - mn);
    m_run = mn;
    float rs = 0.0f;
#pragma unroll
    for (int t4 = 0; t4 < 4; ++t4)
#pragma unroll
      for (int r = 0; r < 4; ++r) {
        float pv = __expf(st[t4][r] - mn);
        st[t4][r] = pv;
        rs += pv;
      }
    rs += __shfl_xor(rs, 16);
    rs += __shfl_xor(rs, 32);
    l_run = l_run * al + rs;

    // ---- rescale O: need al for q = lq*4+r (al lives at lane lr=q) ----
    floatx4 av;
#pragma unroll
    for (int r = 0; r < 4; ++r) av[r] = __shfl(al, lq * 4 + r);
#pragma unroll
    for (int dt = 0; dt < 8; ++dt) of[dt] *= av;

    // ---- P^T -> P via per-wave LDS (pack bf16 pairs, dword stores) ----
#pragma unroll
    for (int t4 = 0; t4 < 4; ++t4) {
      unsigned* pdst = (unsigned*)(Ps + (wv * 16 + lr) * 72 + t4 * 16 + lq * 4);
      pdst[0] = pk_bf16(st[t4][0], st[t4][1]);
      pdst[1] = pk_bf16(st[t4][2], st[t4][3]);
    }

    // ---- O += P V ----
#pragma unroll
    for (int ks = 0; ks < 2; ++ks) {
      short8 pa = *(const short8*)(Ps + (wv * 16 + lr) * 72 + ks * 32 + lq * 8);
#pragma unroll
      for (int dt = 0; dt < 8; ++dt) {
        short8 vb = *(const short8*)(Vt + ((ks * 4 + lq) * 128 + dt * 16 + lr) * 8);
        of[dt] = __builtin_amdgcn_mfma_f32_16x16x32_bf16(pa, vb, of[dt], 0, 0, 0);
      }
    }
    __syncthreads();
  }

  // ---- epilogue: O /= l ----
  float linv = 1.0f / l_run;
  floatx4 lv;
#pragma unroll
  for (int r = 0; r < 4; ++r) lv[r] = __shfl(linv, lq * 4 + r);
#pragma unroll
  for (int dt = 0; dt < 8; ++dt)
#pragma unroll
    for (int r = 0; r < 4; ++r)
      outp[(brow + q0w + lq * 4 + r) * C_ + h * DH + dt * 16 + lr] =
          __float2bfloat16(of[dt][r] * lv[r]);
}

extern "C" void kernel_launch(void* const* d_in, const int* in_sizes, int n_in,
                              void* d_out, int out_size, void* d_ws, size_t ws_size,
                              hipStream_t stream) {
  const float* x = (const float*)d_in[0];      // [4096][2048]
  const float* Wqkv = (const float*)d_in[1];   // [2048][6144]
  const float* Wproj = (const float*)d_in[2];  // [2048][2048]

  // workspace layout (bf16), with reuse
  __hip_bfloat16* xb = (__hip_bfloat16*)d_ws;              // 4096*2048
  __hip_bfloat16* WqkvT = xb + (size_t)4096 * 2048;        // 6144*2048
  __hip_bfloat16* qkvb = WqkvT + (size_t)6144 * 2048;      // 4096*6144
  __hip_bfloat16* WprojT = WqkvT;                          // 2048*2048 (after GEMM1)
  __hip_bfloat16* vt_tiles = WqkvT + (size_t)2048 * 2048;  // 2*16*32*8192 (after GEMM1)
  __hip_bfloat16* attnb = xb;                              // 4096*2048 (after GEMM1)

  cast_bf16_kernel<<<8192, 256, 0, stream>>>(x, xb, (4096 * 2048) / 4);
  transpose_cast_kernel<<<dim3(6144 / 32, 2048 / 32), 256, 0, stream>>>(Wqkv, WqkvT, 2048, 6144);

  gemm_bt_kernel<false><<<dim3(6144 / 128, 4096 / 128), 256, 0, stream>>>(
      xb, WqkvT, (void*)qkvb, 4096, 6144, 2048);

  rope_kernel<<<(B_ * S_ * H_ * 64) / 256, 256, 0, stream>>>(qkvb);

  vtrans_kernel<<<dim3(32, 32), 256, 0, stream>>>(qkvb, vt_tiles);

  transpose_cast_kernel<<<dim3(2048 / 32, 2048 / 32), 256, 0, stream>>>(Wproj, WprojT, 2048, 2048);

  attn_kernel<<<dim3(32, 32), 256, 0, stream>>>(qkvb, vt_tiles, attnb);

  gemm_bt_kernel<true><<<dim3(2048 / 128, 4096 / 128), 256, 0, stream>>>(
      attnb, WprojT, d_out, 4096, 2048, 2048);
}

// Round 3
// 440.958 us; speedup vs baseline: 1.3413x; 1.0730x over previous
//
#include <hip/hip_runtime.h>
#include <hip/hip_bf16.h>

// Problem constants
#define B_   2
#define S_   2048
#define C_   2048
#define H_   16
#define DH   128
#define C3   (3 * C_)

typedef __attribute__((ext_vector_type(8))) short short8;
typedef __attribute__((ext_vector_type(4))) float floatx4;

__device__ __forceinline__ void gload16(const void* g, void* l) {
  __builtin_amdgcn_global_load_lds(
      (const __attribute__((address_space(1))) unsigned int*)g,
      (__attribute__((address_space(3))) unsigned int*)l, 16, 0, 0);
}

__device__ __forceinline__ unsigned pk_bf16(float a, float b) {
  union { __hip_bfloat16 h; unsigned short u; } ua, ub;
  ua.h = __float2bfloat16(a); ub.h = __float2bfloat16(b);
  return (unsigned)ua.u | ((unsigned)ub.u << 16);
}

// ---------------- cast f32 -> bf16 ----------------
__global__ __launch_bounds__(256) void cast_bf16_kernel(
    const float* __restrict__ in, __hip_bfloat16* __restrict__ out, int n4) {
  int i = blockIdx.x * blockDim.x + threadIdx.x;
  if (i >= n4) return;
  float4 v = ((const float4*)in)[i];
  union { __hip_bfloat16 b[4]; uint2 u; } t;
  t.b[0] = __float2bfloat16(v.x);
  t.b[1] = __float2bfloat16(v.y);
  t.b[2] = __float2bfloat16(v.z);
  t.b[3] = __float2bfloat16(v.w);
  ((uint2*)out)[i] = t.u;
}

// ---------------- transpose + cast: in[R][Cc] f32 -> out[Cc][R] bf16 ----------------
__global__ __launch_bounds__(256) void transpose_cast_kernel(
    const float* __restrict__ in, __hip_bfloat16* __restrict__ out, int R, int Cc) {
  __shared__ float tile[32][33];
  int c0 = blockIdx.x * 32, r0 = blockIdx.y * 32;
  int tx = threadIdx.x & 31, ty = threadIdx.x >> 5;  // ty: 0..7
#pragma unroll
  for (int k = 0; k < 4; ++k)
    tile[ty + 8 * k][tx] = in[(size_t)(r0 + ty + 8 * k) * Cc + c0 + tx];
  __syncthreads();
#pragma unroll
  for (int k = 0; k < 4; ++k)
    out[(size_t)(c0 + ty + 8 * k) * R + r0 + tx] = __float2bfloat16(tile[tx][ty + 8 * k]);
}

// ---------------- GEMM: C[M][N] = A[M][K] * Bt[N][K]^T  (m97 structure) ----------------
template <bool OUT_F32>
__global__ __launch_bounds__(256) void gemm_bt_kernel(
    const __hip_bfloat16* __restrict__ A, const __hip_bfloat16* __restrict__ Bt,
    void* __restrict__ Cp, int M, int N, int K) {
  __shared__ __hip_bfloat16 As[128 * 32];
  __shared__ __hip_bfloat16 Bs[128 * 32];
  const int tid = threadIdx.x;
  const int lane = tid & 63, wv = tid >> 6;
  const int wm = wv >> 1, wn = wv & 1;
  const int lr = lane & 15, lq = lane >> 4;
  const int m0 = blockIdx.y * 128, n0 = blockIdx.x * 128;

  floatx4 acc[4][4] = {};

  for (int k0 = 0; k0 < K; k0 += 32) {
#pragma unroll
    for (int p = 0; p < 2; ++p) {
      int c = p * 256 + wv * 64 + lane;
      int row = c >> 2, ko = (c & 3) << 3;
      gload16(A + (size_t)(m0 + row) * K + k0 + ko,
              (char*)As + (size_t)(p * 256 + wv * 64) * 16);
      gload16(Bt + (size_t)(n0 + row) * K + k0 + ko,
              (char*)Bs + (size_t)(p * 256 + wv * 64) * 16);
    }
    __syncthreads();
    short8 af[4], bf[4];
#pragma unroll
    for (int i = 0; i < 4; ++i)
      af[i] = *(const short8*)(As + (wm * 64 + i * 16 + lr) * 32 + lq * 8);
#pragma unroll
    for (int j = 0; j < 4; ++j)
      bf[j] = *(const short8*)(Bs + (wn * 64 + j * 16 + lr) * 32 + lq * 8);
#pragma unroll
    for (int i = 0; i < 4; ++i)
#pragma unroll
      for (int j = 0; j < 4; ++j)
        acc[i][j] = __builtin_amdgcn_mfma_f32_16x16x32_bf16(af[i], bf[j], acc[i][j], 0, 0, 0);
    __syncthreads();
  }

#pragma unroll
  for (int i = 0; i < 4; ++i)
#pragma unroll
    for (int j = 0; j < 4; ++j)
#pragma unroll
      for (int r = 0; r < 4; ++r) {
        int row = m0 + wm * 64 + i * 16 + lq * 4 + r;
        int col = n0 + wn * 64 + j * 16 + lr;
        if (OUT_F32)
          ((float*)Cp)[(size_t)row * N + col] = acc[i][j][r];
        else
          ((__hip_bfloat16*)Cp)[(size_t)row * N + col] = __float2bfloat16(acc[i][j][r]);
      }
}

// ---------------- RoPE over k (cols 0..C) and q (cols C..2C) of qkv; scales q ----------------
__global__ __launch_bounds__(256) void rope_kernel(__hip_bfloat16* __restrict__ qkv) {
  int i = blockIdx.x * blockDim.x + threadIdx.x;  // B*S*H*64 threads
  int d = i & 63;
  int h = (i >> 6) & 15;
  int row = i >> 10;        // 0..4095
  int s = row & (S_ - 1);
  float invf = exp2f((float)d * (-13.287712379549449f / 64.0f));  // 10000^(-d/64)
  float ang = (float)s * invf;
  float sn, c;
  __sincosf(ang, &sn, &c);
  size_t base = (size_t)row * C3 + h * DH + d;
  float k1 = __bfloat162float(qkv[base]);
  float k2 = __bfloat162float(qkv[base + 64]);
  qkv[base]      = __float2bfloat16(k1 * c - k2 * sn);
  qkv[base + 64] = __float2bfloat16(k2 * c + k1 * sn);
  const float scale = 0.08838834764831845f;  // 1/sqrt(128)
  float q1 = __bfloat162float(qkv[base + C_]);
  float q2 = __bfloat162float(qkv[base + C_ + 64]);
  qkv[base + C_]      = __float2bfloat16((q1 * c - q2 * sn) * scale);
  qkv[base + C_ + 64] = __float2bfloat16((q2 * c + q1 * sn) * scale);
}

// ---------------- V pre-transpose into tiled [bh][kt][chunk16] layout ----------------
// Tile (bh, t): V^T block [128 d][64 s]; chunk L = cs*128 + d holds V[t*64+cs*8+j][d], j=0..7.
__global__ __launch_bounds__(256) void vtrans_kernel(
    const __hip_bfloat16* __restrict__ qkv, __hip_bfloat16* __restrict__ vt) {
  __shared__ short T[64 * 144];  // [s][d], pitch 144 (16B-aligned rows)
  const int tid = threadIdx.x;
  const int t = blockIdx.x, bh = blockIdx.y;
  const int b = bh >> 4, h = bh & 15;
  const size_t brow = (size_t)b * S_;
#pragma unroll
  for (int p = 0; p < 4; ++p) {
    int idx = p * 256 + tid;
    int row = idx >> 4, c8 = idx & 15;
    *(short8*)(T + row * 144 + c8 * 8) =
        *(const short8*)(qkv + (brow + t * 64 + row) * C3 + 2 * C_ + h * DH + c8 * 8);
  }
  __syncthreads();
#pragma unroll
  for (int p = 0; p < 4; ++p) {
    int L = p * 256 + tid;
    int d = L & 127, cs = L >> 7;
    short8 v;
#pragma unroll
    for (int j = 0; j < 8; ++j) v[j] = T[(cs * 8 + j) * 144 + d];
    *(short8*)(vt + ((size_t)bh * 32 + t) * 8192 + (size_t)L * 8) = v;
  }
}

// ---------------- Flash attention (transposed-S, BQ=128: 4 waves x 32 q-rows) ----------------
// Grid (16 qtiles, 32 bh), block 256 = 4 waves. BKT=64.
// St = mfma(Kfrag, Qfrag): k in regs, q in lanes -> softmax = 2 per-lane scalar chains.
__global__ __launch_bounds__(256, 2) void attn_kernel(
    const __hip_bfloat16* __restrict__ qkv,
    const __hip_bfloat16* __restrict__ vt_tiles,
    __hip_bfloat16* __restrict__ outp) {
  __shared__ __hip_bfloat16 Ks[64 * 128];    // xor-swizzled 16B chunks
  __shared__ __hip_bfloat16 Vt[64 * 128];    // chunk L = cs*128 + d (matches vt_tiles)
  __shared__ __hip_bfloat16 Ps[4 * 32 * 72]; // per-wave P [32 q][64 s], pitch 72

  const int tid = threadIdx.x, lane = tid & 63, wv = tid >> 6;
  const int lr = lane & 15, lq = lane >> 4;
  const int qt = gridDim.x - 1 - blockIdx.x;  // heavy tiles first
  const int bh = blockIdx.y;
  const int b = bh >> 4, h = bh & 15;
  const int q0 = qt * 128;
  const int q0w = q0 + wv * 32;
  const size_t brow = (size_t)b * S_;

  // Q fragments (B-operand layout): q = q0w + rt*16 + lr, k-chunk lq*8
  short8 qf[2][4];
#pragma unroll
  for (int rt = 0; rt < 2; ++rt)
#pragma unroll
    for (int ks = 0; ks < 4; ++ks)
      qf[rt][ks] = *(const short8*)(qkv + (brow + q0w + rt * 16 + lr) * C3 + C_ + h * DH + ks * 32 + lq * 8);

  floatx4 of[2][8] = {};           // O accum: q = rt*16 + lq*4 + r (rel), d = dt*16 + lr
  float m_run[2] = {-1e30f, -1e30f}, l_run[2] = {0.0f, 0.0f};  // per-lane, q = q0w + rt*16 + lr

  const int wrow_last = q0w + 31;
  const int nkt = 2 * qt + 2;
  for (int kt = 0; kt < nkt; ++kt) {
    const int kb = kt * 64;
    // ---- stage K (swizzled) and V (pre-tiled) via async DMA ----
#pragma unroll
    for (int p = 0; p < 4; ++p) {
      int L = p * 256 + wv * 64 + lane;
      int srow = L >> 4;
      int ck = (L & 15) ^ (srow & 15);
      gload16(qkv + (brow + kb + srow) * C3 + h * DH + ck * 8,
              (char*)Ks + (size_t)(p * 256 + wv * 64) * 16);
      gload16(vt_tiles + ((size_t)bh * 32 + kt) * 8192 + (size_t)L * 8,
              (char*)Vt + (size_t)(p * 256 + wv * 64) * 16);
    }
    __syncthreads();

    if (kb <= wrow_last) {  // wave-uniform
      // ---- St = K Q^T : st[rt][t4][r] -> s = kb + t4*16 + lq*4 + r, q = q0w + rt*16 + lr ----
      floatx4 st[2][4] = {};
#pragma unroll
      for (int ks = 0; ks < 4; ++ks) {
        short8 kfr[4];
#pragma unroll
        for (int t4 = 0; t4 < 4; ++t4)
          kfr[t4] = *(const short8*)(Ks + ((t4 * 16 + lr) * 16 + ((ks * 4 + lq) ^ lr)) * 8);
#pragma unroll
        for (int rt = 0; rt < 2; ++rt)
#pragma unroll
          for (int t4 = 0; t4 < 4; ++t4)
            st[rt][t4] = __builtin_amdgcn_mfma_f32_16x16x32_bf16(kfr[t4], qf[rt][ks], st[rt][t4], 0, 0, 0);
      }

      // ---- causal mask (tiles intersecting this wave's diagonal) ----
      if (kb + 63 > q0w) {
#pragma unroll
        for (int rt = 0; rt < 2; ++rt)
#pragma unroll
          for (int t4 = 0; t4 < 4; ++t4)
#pragma unroll
            for (int r = 0; r < 4; ++r) {
              int s = kb + t4 * 16 + lq * 4 + r;
              if (s > q0w + rt * 16 + lr) st[rt][t4][r] = -1e30f;
            }
      }

      // ---- online softmax: two independent per-lane scalar chains (rt=0,1) ----
      float al[2];
#pragma unroll
      for (int rt = 0; rt < 2; ++rt) {
        float tm = -1e30f;
#pragma unroll
        for (int t4 = 0; t4 < 4; ++t4)
#pragma unroll
          for (int r = 0; r < 4; ++r) tm = fmaxf(tm, st[rt][t4][r]);
        tm = fmaxf(tm, __shfl_xor(tm, 16));
        tm = fmaxf(tm, __shfl_xor(tm, 32));
        float mn = fmaxf(m_run[rt], tm);
        al[rt] = __expf(m_run[rt] - mn);
        m_run[rt] = mn;
        float rs = 0.0f;
#pragma unroll
        for (int t4 = 0; t4 < 4; ++t4)
#pragma unroll
          for (int r = 0; r < 4; ++r) {
            float pv = __expf(st[rt][t4][r] - mn);
            st[rt][t4][r] = pv;
            rs += pv;
          }
        rs += __shfl_xor(rs, 16);
        rs += __shfl_xor(rs, 32);
        l_run[rt] = l_run[rt] * al[rt] + rs;
      }

      // ---- rescale O: need al[rt] for q-rel = lq*4 + r (al lives at lane lr = q-rel) ----
#pragma unroll
      for (int rt = 0; rt < 2; ++rt) {
        floatx4 av;
#pragma unroll
        for (int r = 0; r < 4; ++r) av[r] = __shfl(al[rt], lq * 4 + r);
#pragma unroll
        for (int dt = 0; dt < 8; ++dt) of[rt][dt] *= av;
      }

      // ---- P^T -> P via per-wave LDS (pack bf16 pairs, dword stores) ----
#pragma unroll
      for (int rt = 0; rt < 2; ++rt)
#pragma unroll
        for (int t4 = 0; t4 < 4; ++t4) {
          unsigned* pdst = (unsigned*)(Ps + (wv * 32 + rt * 16 + lr) * 72 + t4 * 16 + lq * 4);
          pdst[0] = pk_bf16(st[rt][t4][0], st[rt][t4][1]);
          pdst[1] = pk_bf16(st[rt][t4][2], st[rt][t4][3]);
        }

      // ---- O += P V ----
#pragma unroll
      for (int ks = 0; ks < 2; ++ks) {
        short8 pa[2];
#pragma unroll
        for (int rt = 0; rt < 2; ++rt)
          pa[rt] = *(const short8*)(Ps + (wv * 32 + rt * 16 + lr) * 72 + ks * 32 + lq * 8);
#pragma unroll
        for (int dt = 0; dt < 8; ++dt) {
          short8 vb = *(const short8*)(Vt + ((ks * 4 + lq) * 128 + dt * 16 + lr) * 8);
#pragma unroll
          for (int rt = 0; rt < 2; ++rt)
            of[rt][dt] = __builtin_amdgcn_mfma_f32_16x16x32_bf16(pa[rt], vb, of[rt][dt], 0, 0, 0);
        }
      }
    }
    __syncthreads();
  }

  // ---- epilogue: O /= l ----
#pragma unroll
  for (int rt = 0; rt < 2; ++rt) {
    float linv = 1.0f / l_run[rt];
    floatx4 lv;
#pragma unroll
    for (int r = 0; r < 4; ++r) lv[r] = __shfl(linv, lq * 4 + r);
#pragma unroll
    for (int dt = 0; dt < 8; ++dt)
#pragma unroll
      for (int r = 0; r < 4; ++r)
        outp[(brow + q0w + rt * 16 + lq * 4 + r) * C_ + h * DH + dt * 16 + lr] =
            __float2bfloat16(of[rt][dt][r] * lv[r]);
  }
}

extern "C" void kernel_launch(void* const* d_in, const int* in_sizes, int n_in,
                              void* d_out, int out_size, void* d_ws, size_t ws_size,
                              hipStream_t stream) {
  const float* x = (const float*)d_in[0];      // [4096][2048]
  const float* Wqkv = (const float*)d_in[1];   // [2048][6144]
  const float* Wproj = (const float*)d_in[2];  // [2048][2048]

  // workspace layout (bf16), with reuse
  __hip_bfloat16* xb = (__hip_bfloat16*)d_ws;              // 4096*2048
  __hip_bfloat16* WqkvT = xb + (size_t)4096 * 2048;        // 6144*2048
  __hip_bfloat16* qkvb = WqkvT + (size_t)6144 * 2048;      // 4096*6144
  __hip_bfloat16* WprojT = WqkvT;                          // 2048*2048 (after GEMM1)
  __hip_bfloat16* vt_tiles = WqkvT + (size_t)2048 * 2048;  // 2*16*32*8192 (after GEMM1)
  __hip_bfloat16* attnb = xb;                              // 4096*2048 (after GEMM1)

  cast_bf16_kernel<<<8192, 256, 0, stream>>>(x, xb, (4096 * 2048) / 4);
  transpose_cast_kernel<<<dim3(6144 / 32, 2048 / 32), 256, 0, stream>>>(Wqkv, WqkvT, 2048, 6144);

  gemm_bt_kernel<false><<<dim3(6144 / 128, 4096 / 128), 256, 0, stream>>>(
      xb, WqkvT, (void*)qkvb, 4096, 6144, 2048);

  rope_kernel<<<(B_ * S_ * H_ * 64) / 256, 256, 0, stream>>>(qkvb);

  vtrans_kernel<<<dim3(32, 32), 256, 0, stream>>>(qkvb, vt_tiles);

  transpose_cast_kernel<<<dim3(2048 / 32, 2048 / 32), 256, 0, stream>>>(Wproj, WprojT, 2048, 2048);

  attn_kernel<<<dim3(16, 32), 256, 0, stream>>>(qkvb, vt_tiles, attnb);

  gemm_bt_kernel<true><<<dim3(2048 / 128, 4096 / 128), 256, 0, stream>>>(
      attnb, WprojT, d_out, 4096, 2048, 2048);
}